// Round 12
// baseline (355.699 us; speedup 1.0000x reference)
//
#include <hip/hip_runtime.h>
#include <hip/hip_fp16.h>

#define NN 50000
#define NEG_SLOPE 0.2f
#define BSHIFT 9
#define BNODES (1 << BSHIFT)                          // 512 nodes per bucket
#define NBUCK ((NN + BNODES - 1) >> BSHIFT)           // 98
#define BCAP 18432                                    // E/NBUCK=16384 avg, +16 sigma

// ---- pass A: coarse bucket binning of (src,dst) by dst>>9 ----
// bucket_cursor[b] is RELATIVE to region start (memset-0 init)
__global__ __launch_bounds__(1024) void bucketA(
        const int* __restrict__ src, const int* __restrict__ dst,
        unsigned* __restrict__ bucket_cursor, int2* __restrict__ ebuf, int E) {
    __shared__ unsigned hist[NBUCK];
    int tid = threadIdx.x;
    if (tid < NBUCK) hist[tid] = 0u;
    __syncthreads();
    int e = blockIdx.x * 1024 + tid;
    int s = 0, d = 0, b = 0;
    bool valid = e < E;
    if (valid) {
        s = src[e]; d = dst[e]; b = d >> BSHIFT;
        atomicAdd(&hist[b], 1u);
    }
    __syncthreads();
    if (tid < NBUCK) {
        unsigned c = hist[tid];
        hist[tid] = c ? (unsigned)(tid * BCAP) + atomicAdd(&bucket_cursor[tid], c) : 0u;
    }
    __syncthreads();
    if (valid) {
        unsigned slot = atomicAdd(&hist[b], 1u);
        ebuf[slot] = make_int2(s, d);
    }
}

// ===== z1 = h @ W1 (fp16 out) + el1/er1 — 64x128 block, 8 rows x 4 cols/thread.
//       W1 streamed from global (L2-resident) -> LDS pipe only carries h. =====
__global__ __launch_bounds__(256) void gemm1_kernel(
        const float* __restrict__ h, const float* __restrict__ W1,
        const float* __restrict__ al1, const float* __restrict__ ar1,
        __half* __restrict__ z1h, float* __restrict__ el1, float* __restrict__ er1, int N) {
    __shared__ float hs[64][132];     // +4 pad: bank spread
    int tid = threadIdx.x;
    int gc = tid & 31, gr = tid >> 5;            // rows gr*8..+7, cols gc+32i (head i)
    int row0 = blockIdx.x * 64;
    int nrow = min(64, N - row0);

    for (int idx = tid; idx < nrow * 32; idx += 256) {
        int row = idx >> 5, kq = idx & 31;
        *(float4*)&hs[row][kq * 4] = ((const float4*)(h + (size_t)(row0 + row) * 128))[kq];
    }
    __syncthreads();

    float acc[8][4];
    #pragma unroll
    for (int j = 0; j < 8; ++j)
        #pragma unroll
        for (int i = 0; i < 4; ++i) acc[j][i] = 0.f;

    for (int k = 0; k < 128; k += 4) {
        float w[4][4];
        #pragma unroll
        for (int kk = 0; kk < 4; ++kk)
            #pragma unroll
            for (int i = 0; i < 4; ++i)
                w[kk][i] = W1[(k + kk) * 128 + gc + 32 * i];
        #pragma unroll
        for (int j = 0; j < 8; ++j) {
            float4 hv = *(const float4*)&hs[gr * 8 + j][k];
            #pragma unroll
            for (int i = 0; i < 4; ++i)
                acc[j][i] = fmaf(hv.x, w[0][i], fmaf(hv.y, w[1][i],
                            fmaf(hv.z, w[2][i], fmaf(hv.w, w[3][i], acc[j][i]))));
        }
    }

    float a_l[4], a_r[4];
    #pragma unroll
    for (int i = 0; i < 4; ++i) { a_l[i] = al1[gc + 32 * i]; a_r[i] = ar1[gc + 32 * i]; }

    #pragma unroll
    for (int j = 0; j < 8; ++j) {
        int row = gr * 8 + j;
        bool live = row < nrow;
        int node = row0 + row;
        if (live) {
            #pragma unroll
            for (int i = 0; i < 4; ++i)
                z1h[(size_t)node * 128 + gc + 32 * i] = __float2half(acc[j][i]);
        }
        float pl[4], pr[4];
        #pragma unroll
        for (int i = 0; i < 4; ++i) { pl[i] = acc[j][i] * a_l[i]; pr[i] = acc[j][i] * a_r[i]; }
        #pragma unroll
        for (int o = 16; o; o >>= 1) {
            #pragma unroll
            for (int i = 0; i < 4; ++i) {
                pl[i] += __shfl_xor(pl[i], o, 32);
                pr[i] += __shfl_xor(pr[i], o, 32);
            }
        }
        if (live && gc == 0) {
            #pragma unroll
            for (int i = 0; i < 4; ++i) {
                el1[node * 4 + i] = pl[i];
                er1[node * 4 + i] = pr[i];
            }
        }
    }
}

// ---- scatterC: per-bucket LDS hist/scan/rank; writes off[], src_sorted[],
//      per-edge fp16 alpha (exp of leaky score), and per-node 1/sum (invs1) ----
__global__ __launch_bounds__(1024) void scatterC(
        const int2* __restrict__ ebuf, const unsigned* __restrict__ bucket_cursor,
        const float* __restrict__ el1, const float* __restrict__ er1,
        unsigned* __restrict__ off, int* __restrict__ src_sorted,
        uint2* __restrict__ alpha1p, float* __restrict__ invs1, int N, int E) {
    __shared__ unsigned hist[BNODES], nodeoff[BNODES], wsum[8], bsz[128];
    __shared__ float4 er_s[BNODES];
    __shared__ float nsum[BNODES][4];
    int b = blockIdx.x, tid = threadIdx.x;
    int base = b << BSHIFT;
    unsigned rs = (unsigned)(b * BCAP), re = rs + bucket_cursor[b];
    const float4* el1v = (const float4*)el1;
    const float4* er1v = (const float4*)er1;

    if (tid < 128) bsz[tid] = (tid < NBUCK) ? bucket_cursor[tid] : 0u;
    if (tid < BNODES) {
        hist[tid] = 0u;
        int n = base + tid;
        er_s[tid] = (n < N) ? er1v[n] : make_float4(0.f, 0.f, 0.f, 0.f);
        nsum[tid][0] = 0.f; nsum[tid][1] = 0.f; nsum[tid][2] = 0.f; nsum[tid][3] = 0.f;
    }
    __syncthreads();
    if (tid == 0) {
        unsigned r = 0;
        for (int t = 0; t < NBUCK; ++t) { unsigned c = bsz[t]; bsz[t] = r; r += c; }
        if (b == 0) off[N] = (unsigned)E;
    }
    __syncthreads();
    unsigned boff = bsz[b];

    for (unsigned i = rs + tid; i < re; i += 1024)
        atomicAdd(&hist[ebuf[i].y - base], 1u);
    __syncthreads();
    unsigned v = 0, x = 0;
    int lane = tid & 63, wv = tid >> 6;
    if (tid < BNODES) {
        v = hist[tid]; x = v;
        #pragma unroll
        for (int o = 1; o < 64; o <<= 1) {
            unsigned n = __shfl_up(x, o, 64);
            if (lane >= o) x += n;
        }
        if (lane == 63) wsum[wv] = x;
    }
    __syncthreads();
    if (tid == 0) {
        unsigned r = 0;
        #pragma unroll
        for (int k = 0; k < 8; ++k) { unsigned t = wsum[k]; wsum[k] = r; r += t; }
    }
    __syncthreads();
    if (tid < BNODES) {
        unsigned exoff = x - v + wsum[wv] + boff;
        nodeoff[tid] = exoff;
        if (base + tid < N) off[base + tid] = exoff;
        hist[tid] = 0u;
    }
    __syncthreads();
    // rank + write src_sorted, fp16 alpha, and accumulate per-node sums of the
    // SAME quantized alphas (softmax shift dropped: scores bounded, exp-safe)
    for (unsigned i = rs + tid; i < re; i += 1024) {
        int2 ed = ebuf[i];
        int ln = ed.y - base;
        unsigned r = atomicAdd(&hist[ln], 1u);
        unsigned p = nodeoff[ln] + r;
        src_sorted[p] = ed.x;
        float4 el = el1v[ed.x];
        float4 er = er_s[ln];
        float v0 = el.x + er.x; v0 = v0 > 0.f ? v0 : NEG_SLOPE * v0;
        float v1 = el.y + er.y; v1 = v1 > 0.f ? v1 : NEG_SLOPE * v1;
        float v2 = el.z + er.z; v2 = v2 > 0.f ? v2 : NEG_SLOPE * v2;
        float v3 = el.w + er.w; v3 = v3 > 0.f ? v3 : NEG_SLOPE * v3;
        union { __half2 h2[2]; uint2 u; } pk;
        pk.h2[0] = __floats2half2_rn(__expf(v0), __expf(v1));
        pk.h2[1] = __floats2half2_rn(__expf(v2), __expf(v3));
        alpha1p[p] = pk.u;
        float2 q0 = __half22float2(pk.h2[0]);
        float2 q1 = __half22float2(pk.h2[1]);
        atomicAdd(&nsum[ln][0], q0.x);
        atomicAdd(&nsum[ln][1], q0.y);
        atomicAdd(&nsum[ln][2], q1.x);
        atomicAdd(&nsum[ln][3], q1.y);
    }
    __syncthreads();
    if (tid < BNODES && base + tid < N) {
        #pragma unroll
        for (int hh = 0; hh < 4; ++hh) {
            float s = nsum[tid][hh];
            invs1[(base + tid) * 4 + hh] = s > 0.f ? 1.f / s : 0.f;
        }
    }
}

// ====== layer1: pure gather-SpMM (inv precomputed) + bias + elu -> x (fp16). ======
__global__ __launch_bounds__(256) void agg1_spmm(
        const int* __restrict__ src_sorted, const unsigned* __restrict__ off,
        const __half* __restrict__ alpha1h, const float* __restrict__ invs1,
        const __half* __restrict__ z1h, const float* __restrict__ b1,
        __half* __restrict__ x) {
    int tid = threadIdx.x, lane = tid & 63, w = tid >> 6;
    int node = blockIdx.x * 4 + w;
    int start = (int)off[node], end = (int)off[node + 1];
    int g = lane >> 4, l16 = lane & 15, head = l16 >> 2;

    float acc[8];
    #pragma unroll
    for (int jj = 0; jj < 8; ++jj) acc[jj] = 0.f;
    int endm1 = end - 1;
    for (int base = start; base < end; base += 32) {
        #pragma unroll
        for (int t = 0; t < 8; ++t) {               // 32 edges in flight per wave-iter
            int i = base + 4 * t + g;
            int ic = min(i, endm1);                 // clamped: always valid
            int s = src_sorted[ic];
            float a = __half2float(alpha1h[ic * 4 + head]);
            a = (i < end) ? a : 0.f;                // select, not branch
            float4 r = *(const float4*)(z1h + ((size_t)s << 7) + l16 * 8);
            const __half* zh = (const __half*)&r;
            #pragma unroll
            for (int k = 0; k < 8; ++k)             // v_fma_mix_f32
                acc[k] = fmaf(__half2float(zh[k]), a, acc[k]);
        }
    }
    #pragma unroll
    for (int jj = 0; jj < 8; ++jj) {
        acc[jj] += __shfl_xor(acc[jj], 16, 64);
        acc[jj] += __shfl_xor(acc[jj], 32, 64);
    }
    if (g == 0) {
        float inv = invs1[node * 4 + head];
        float xv[8];
        #pragma unroll
        for (int jj = 0; jj < 8; ++jj) {
            float t = acc[jj] * inv + b1[l16 * 8 + jj];
            xv[jj] = t > 0.f ? t : (__expf(t) - 1.f);   // elu
        }
        union { __half2 h2[4]; uint4 u; } pk;
        #pragma unroll
        for (int k = 0; k < 4; ++k) pk.h2[k] = __floats2half2_rn(xv[2 * k], xv[2 * k + 1]);
        *(uint4*)(x + ((size_t)node << 7) + l16 * 8) = pk.u;
    }
}

// ===== z2 = x @ W2 (fp16 in/out) + el2/er2 — 64 rows/block, 4 rows x 2 cols/thread =====
__global__ __launch_bounds__(256) void gemm2el_kernel(
        const __half* __restrict__ x, const float* __restrict__ W2,
        const float* __restrict__ al2, const float* __restrict__ ar2,
        __half* __restrict__ z2h, float* __restrict__ el2, float* __restrict__ er2, int N) {
    __shared__ __half xsh[64][136];   // pad 8 halves
    __shared__ float W2T[32][132];    // [c][k]
    int tid = threadIdx.x;
    int row0 = blockIdx.x * 64;
    int nrow = min(64, N - row0);

    for (int idx = tid; idx < nrow * 16; idx += 256) {
        int r = idx >> 4, kq = idx & 15;
        float4 v = ((const float4*)(x + (size_t)(row0 + r) * 128))[kq];
        *(float4*)&xsh[r][kq * 8] = v;
    }
    for (int idx = tid; idx < 4096; idx += 256) {
        int k = idx >> 5, c = idx & 31;
        W2T[c][k] = W2[idx];
    }
    __syncthreads();

    int gc = tid & 15, gr = tid >> 4;   // rows gr*4+j, cols {gc, gc+16}
    float acc[4][2];
    #pragma unroll
    for (int j = 0; j < 4; ++j) { acc[j][0] = 0.f; acc[j][1] = 0.f; }

    for (int p = 0; p < 32; ++p) {      // k-chunks of 4
        float4 w0 = *(const float4*)&W2T[gc][p * 4];
        float4 w1 = *(const float4*)&W2T[gc + 16][p * 4];
        #pragma unroll
        for (int j = 0; j < 4; ++j) {
            const __half* xr = &xsh[gr * 4 + j][p * 4];
            float x0 = __half2float(xr[0]), x1 = __half2float(xr[1]);
            float x2 = __half2float(xr[2]), x3 = __half2float(xr[3]);
            acc[j][0] = fmaf(x0, w0.x, fmaf(x1, w0.y, fmaf(x2, w0.z, fmaf(x3, w0.w, acc[j][0]))));
            acc[j][1] = fmaf(x0, w1.x, fmaf(x1, w1.y, fmaf(x2, w1.z, fmaf(x3, w1.w, acc[j][1]))));
        }
    }

    float al0 = al2[gc], al1v = al2[gc + 16];
    float ar0 = ar2[gc], ar1v = ar2[gc + 16];
    #pragma unroll
    for (int j = 0; j < 4; ++j) {
        int r = gr * 4 + j;
        int node = row0 + r;
        bool live = r < nrow;
        if (live) {
            z2h[(size_t)node * 32 + gc]      = __float2half(acc[j][0]);
            z2h[(size_t)node * 32 + gc + 16] = __float2half(acc[j][1]);
        }
        float pl = acc[j][0] * al0 + acc[j][1] * al1v;
        float pr = acc[j][0] * ar0 + acc[j][1] * ar1v;
        #pragma unroll
        for (int o = 8; o; o >>= 1) {
            pl += __shfl_xor(pl, o, 16);
            pr += __shfl_xor(pr, o, 16);
        }
        if (live && gc == 0) { el2[node] = pl; er2[node] = pr; }
    }
}

// ====== layer2: single-pass exp + SpMM (fma_mix) + bias -> out (wave/node) ======
__global__ __launch_bounds__(256) void agg2_fused(
        const int* __restrict__ src_sorted, const unsigned* __restrict__ off,
        const float* __restrict__ el2, const float* __restrict__ er2,
        const __half* __restrict__ z2h, const float* __restrict__ b2,
        float* __restrict__ out) {
    int tid = threadIdx.x, lane = tid & 63;
    int node = blockIdx.x * 4 + (tid >> 6);
    int start = (int)off[node], end = (int)off[node + 1];
    float er_d = er2[node];

    int g = lane >> 2, l4 = lane & 3;
    float acc[8];
    #pragma unroll
    for (int jj = 0; jj < 8; ++jj) acc[jj] = 0.f;
    float sloc = 0.f;
    int endm1 = end - 1;
    for (int base = start; base < end; base += 64) {
        #pragma unroll
        for (int t = 0; t < 4; ++t) {               // 64 edges in flight per wave-iter
            int i = base + 16 * t + g;
            int ic = min(i, endm1);
            int s = src_sorted[ic];
            float v = el2[s] + er_d;
            v = v > 0.f ? v : NEG_SLOPE * v;
            float ex = __expf(v);
            ex = (i < end) ? ex : 0.f;
            sloc += (l4 == 0) ? ex : 0.f;
            float4 r = *(const float4*)(z2h + ((size_t)s << 5) + l4 * 8);
            const __half* zh = (const __half*)&r;
            #pragma unroll
            for (int k = 0; k < 8; ++k)
                acc[k] = fmaf(__half2float(zh[k]), ex, acc[k]);
        }
    }
    #pragma unroll
    for (int jj = 0; jj < 8; ++jj) {
        acc[jj] += __shfl_xor(acc[jj], 4, 64);
        acc[jj] += __shfl_xor(acc[jj], 8, 64);
        acc[jj] += __shfl_xor(acc[jj], 16, 64);
        acc[jj] += __shfl_xor(acc[jj], 32, 64);
    }
    #pragma unroll
    for (int o = 32; o; o >>= 1) sloc += __shfl_xor(sloc, o, 64);
    float inv = sloc > 0.f ? 1.f / sloc : 0.f;
    if (g == 0) {
        #pragma unroll
        for (int jj = 0; jj < 8; ++jj)
            out[(size_t)node * 32 + l4 * 8 + jj] = acc[jj] * inv + b2[l4 * 8 + jj];
    }
}

extern "C" void kernel_launch(void* const* d_in, const int* in_sizes, int n_in,
                              void* d_out, int out_size, void* d_ws, size_t ws_size,
                              hipStream_t stream) {
    const float* h   = (const float*)d_in[0];
    const int*   src = (const int*)d_in[1];
    const int*   dst = (const int*)d_in[2];
    const float* W1  = (const float*)d_in[3];
    const float* al1 = (const float*)d_in[4];
    const float* ar1 = (const float*)d_in[5];
    const float* b1  = (const float*)d_in[6];
    const float* W2  = (const float*)d_in[7];
    const float* al2 = (const float*)d_in[8];
    const float* ar2 = (const float*)d_in[9];
    const float* b2  = (const float*)d_in[10];
    float* out = (float*)d_out;
    const int N = NN;
    const int E = in_sizes[1];

    char* w = (char*)d_ws;
    __half* z1h       = (__half*)w;   w += (size_t)N * 128 * 2;
    __half* z2h       = (__half*)w;   w += (size_t)N * 32 * 2;
    __half* xh        = (__half*)w;   w += (size_t)N * 128 * 2;
    int2*  ebuf       = (int2*)w;     w += (size_t)NBUCK * BCAP * 8;
    uint2* alpha1p    = (uint2*)w;    w += (size_t)E * 8;
    int*   src_sorted = (int*)w;      w += (size_t)E * 4;
    float* el1        = (float*)w;    w += (size_t)N * 4 * 4;
    float* er1        = (float*)w;    w += (size_t)N * 4 * 4;
    float* invs1      = (float*)w;    w += (size_t)N * 4 * 4;
    float* el2        = (float*)w;    w += (size_t)N * 4;
    float* er2        = (float*)w;    w += (size_t)N * 4;
    unsigned* off     = (unsigned*)w; w += (size_t)(N + 16) * 4;
    unsigned* bucket_cursor = (unsigned*)w; w += 128 * 4;

    hipMemsetAsync(bucket_cursor, 0, 128 * sizeof(unsigned), stream);
    bucketA<<<(E + 1023) / 1024, 1024, 0, stream>>>(src, dst, bucket_cursor, ebuf, E);
    gemm1_kernel<<<(N + 63) / 64, 256, 0, stream>>>(h, W1, al1, ar1, z1h, el1, er1, N);
    scatterC<<<NBUCK, 1024, 0, stream>>>(ebuf, bucket_cursor, el1, er1,
                                         off, src_sorted, alpha1p, invs1, N, E);
    agg1_spmm<<<N / 4, 256, 0, stream>>>(src_sorted, off, (const __half*)alpha1p, invs1,
                                         z1h, b1, xh);
    gemm2el_kernel<<<(N + 63) / 64, 256, 0, stream>>>(xh, W2, al2, ar2, z2h, el2, er2, N);
    agg2_fused<<<N / 4, 256, 0, stream>>>(src_sorted, off, el2, er2, z2h, b2, out);
}

// Round 13
// 320.108 us; speedup vs baseline: 1.1112x; 1.1112x over previous
//
#include <hip/hip_runtime.h>
#include <hip/hip_fp16.h>

#define NN 50000
#define NEG_SLOPE 0.2f
#define BSHIFT 9
#define BNODES (1 << BSHIFT)                          // 512 nodes per bucket
#define NBUCK ((NN + BNODES - 1) >> BSHIFT)           // 98
#define BCAP 18432                                    // E/NBUCK=16384 avg, +16 sigma

// ---- pass A: coarse bucket binning of (src,dst) by dst>>9 ----
// bucket_cursor[b] is RELATIVE to region start (memset-0 init)
__global__ __launch_bounds__(1024) void bucketA(
        const int* __restrict__ src, const int* __restrict__ dst,
        unsigned* __restrict__ bucket_cursor, int2* __restrict__ ebuf, int E) {
    __shared__ unsigned hist[NBUCK];
    int tid = threadIdx.x;
    if (tid < NBUCK) hist[tid] = 0u;
    __syncthreads();
    int e = blockIdx.x * 1024 + tid;
    int s = 0, d = 0, b = 0;
    bool valid = e < E;
    if (valid) {
        s = src[e]; d = dst[e]; b = d >> BSHIFT;
        atomicAdd(&hist[b], 1u);
    }
    __syncthreads();
    if (tid < NBUCK) {
        unsigned c = hist[tid];
        hist[tid] = c ? (unsigned)(tid * BCAP) + atomicAdd(&bucket_cursor[tid], c) : 0u;
    }
    __syncthreads();
    if (valid) {
        unsigned slot = atomicAdd(&hist[b], 1u);
        ebuf[slot] = make_int2(s, d);
    }
}

// ===== z1 = h @ W1 (fp16 out) + el1/er1 — 64x128 block, 8 rows x 4 cols/thread.
//       W1 streamed from global (L2-resident) -> LDS pipe only carries h. =====
__global__ __launch_bounds__(256) void gemm1_kernel(
        const float* __restrict__ h, const float* __restrict__ W1,
        const float* __restrict__ al1, const float* __restrict__ ar1,
        __half* __restrict__ z1h, float* __restrict__ el1, float* __restrict__ er1, int N) {
    __shared__ float hs[64][132];     // +4 pad: bank spread
    int tid = threadIdx.x;
    int gc = tid & 31, gr = tid >> 5;            // rows gr*8..+7, cols gc+32i (head i)
    int row0 = blockIdx.x * 64;
    int nrow = min(64, N - row0);

    for (int idx = tid; idx < nrow * 32; idx += 256) {
        int row = idx >> 5, kq = idx & 31;
        *(float4*)&hs[row][kq * 4] = ((const float4*)(h + (size_t)(row0 + row) * 128))[kq];
    }
    __syncthreads();

    float acc[8][4];
    #pragma unroll
    for (int j = 0; j < 8; ++j)
        #pragma unroll
        for (int i = 0; i < 4; ++i) acc[j][i] = 0.f;

    for (int k = 0; k < 128; k += 4) {
        float w[4][4];
        #pragma unroll
        for (int kk = 0; kk < 4; ++kk)
            #pragma unroll
            for (int i = 0; i < 4; ++i)
                w[kk][i] = W1[(k + kk) * 128 + gc + 32 * i];
        #pragma unroll
        for (int j = 0; j < 8; ++j) {
            float4 hv = *(const float4*)&hs[gr * 8 + j][k];
            #pragma unroll
            for (int i = 0; i < 4; ++i)
                acc[j][i] = fmaf(hv.x, w[0][i], fmaf(hv.y, w[1][i],
                            fmaf(hv.z, w[2][i], fmaf(hv.w, w[3][i], acc[j][i]))));
        }
    }

    float a_l[4], a_r[4];
    #pragma unroll
    for (int i = 0; i < 4; ++i) { a_l[i] = al1[gc + 32 * i]; a_r[i] = ar1[gc + 32 * i]; }

    #pragma unroll
    for (int j = 0; j < 8; ++j) {
        int row = gr * 8 + j;
        bool live = row < nrow;
        int node = row0 + row;
        if (live) {
            #pragma unroll
            for (int i = 0; i < 4; ++i)
                z1h[(size_t)node * 128 + gc + 32 * i] = __float2half(acc[j][i]);
        }
        float pl[4], pr[4];
        #pragma unroll
        for (int i = 0; i < 4; ++i) { pl[i] = acc[j][i] * a_l[i]; pr[i] = acc[j][i] * a_r[i]; }
        #pragma unroll
        for (int o = 16; o; o >>= 1) {
            #pragma unroll
            for (int i = 0; i < 4; ++i) {
                pl[i] += __shfl_xor(pl[i], o, 32);
                pr[i] += __shfl_xor(pr[i], o, 32);
            }
        }
        if (live && gc == 0) {
            #pragma unroll
            for (int i = 0; i < 4; ++i) {
                el1[node * 4 + i] = pl[i];
                er1[node * 4 + i] = pr[i];
            }
        }
    }
}

// ---- scatterC: per-bucket LDS hist/scan/rank; writes off[], src_sorted[],
//      and per-edge fp16 alpha (exp of leaky score). NO per-node sums here
//      (LDS same-address atomics serialize — R12 lesson). ----
__global__ __launch_bounds__(1024) void scatterC(
        const int2* __restrict__ ebuf, const unsigned* __restrict__ bucket_cursor,
        const float* __restrict__ el1, const float* __restrict__ er1,
        unsigned* __restrict__ off, int* __restrict__ src_sorted,
        uint2* __restrict__ alpha1p, int N, int E) {
    __shared__ unsigned hist[BNODES], nodeoff[BNODES], wsum[8], bsz[128];
    __shared__ float4 er_s[BNODES];
    int b = blockIdx.x, tid = threadIdx.x;
    int base = b << BSHIFT;
    unsigned rs = (unsigned)(b * BCAP), re = rs + bucket_cursor[b];
    const float4* el1v = (const float4*)el1;
    const float4* er1v = (const float4*)er1;

    if (tid < 128) bsz[tid] = (tid < NBUCK) ? bucket_cursor[tid] : 0u;
    if (tid < BNODES) {
        hist[tid] = 0u;
        int n = base + tid;
        er_s[tid] = (n < N) ? er1v[n] : make_float4(0.f, 0.f, 0.f, 0.f);
    }
    __syncthreads();
    if (tid == 0) {
        unsigned r = 0;
        for (int t = 0; t < NBUCK; ++t) { unsigned c = bsz[t]; bsz[t] = r; r += c; }
        if (b == 0) off[N] = (unsigned)E;
    }
    __syncthreads();
    unsigned boff = bsz[b];

    for (unsigned i = rs + tid; i < re; i += 1024)
        atomicAdd(&hist[ebuf[i].y - base], 1u);
    __syncthreads();
    unsigned v = 0, x = 0;
    int lane = tid & 63, wv = tid >> 6;
    if (tid < BNODES) {
        v = hist[tid]; x = v;
        #pragma unroll
        for (int o = 1; o < 64; o <<= 1) {
            unsigned n = __shfl_up(x, o, 64);
            if (lane >= o) x += n;
        }
        if (lane == 63) wsum[wv] = x;
    }
    __syncthreads();
    if (tid == 0) {
        unsigned r = 0;
        #pragma unroll
        for (int k = 0; k < 8; ++k) { unsigned t = wsum[k]; wsum[k] = r; r += t; }
    }
    __syncthreads();
    if (tid < BNODES) {
        unsigned exoff = x - v + wsum[wv] + boff;
        nodeoff[tid] = exoff;
        if (base + tid < N) off[base + tid] = exoff;
        hist[tid] = 0u;
    }
    __syncthreads();
    // rank + write src_sorted and fp16 alpha (softmax shift dropped: bounded scores)
    for (unsigned i = rs + tid; i < re; i += 1024) {
        int2 ed = ebuf[i];
        int ln = ed.y - base;
        unsigned r = atomicAdd(&hist[ln], 1u);
        unsigned p = nodeoff[ln] + r;
        src_sorted[p] = ed.x;
        float4 el = el1v[ed.x];
        float4 er = er_s[ln];
        float v0 = el.x + er.x; v0 = v0 > 0.f ? v0 : NEG_SLOPE * v0;
        float v1 = el.y + er.y; v1 = v1 > 0.f ? v1 : NEG_SLOPE * v1;
        float v2 = el.z + er.z; v2 = v2 > 0.f ? v2 : NEG_SLOPE * v2;
        float v3 = el.w + er.w; v3 = v3 > 0.f ? v3 : NEG_SLOPE * v3;
        union { __half2 h2[2]; uint2 u; } pk;
        pk.h2[0] = __floats2half2_rn(__expf(v0), __expf(v1));
        pk.h2[1] = __floats2half2_rn(__expf(v2), __expf(v3));
        alpha1p[p] = pk.u;
    }
}

// ====== layer1: coalesced alpha-sum pre-pass + pure gather-SpMM + bias + elu -> x ======
__global__ __launch_bounds__(256) void agg1_spmm(
        const int* __restrict__ src_sorted, const unsigned* __restrict__ off,
        const uint2* __restrict__ alpha1p, const __half* __restrict__ z1h,
        const float* __restrict__ b1, __half* __restrict__ x) {
    int tid = threadIdx.x, lane = tid & 63, w = tid >> 6;
    int node = blockIdx.x * 4 + w;
    int start = (int)off[node], end = (int)off[node + 1];
    int g = lane >> 4, l16 = lane & 15, head = l16 >> 2;
    const __half* alpha1h = (const __half*)alpha1p;

    // pre-pass: sums of the SAME quantized alphas, coalesced (no atomics)
    float s0 = 0.f, s1 = 0.f, s2 = 0.f, s3 = 0.f;
    for (int i = start + lane; i < end; i += 64) {
        uint2 u = alpha1p[i];
        float2 q0 = __half22float2(*(const __half2*)&u.x);
        float2 q1 = __half22float2(*(const __half2*)&u.y);
        s0 += q0.x; s1 += q0.y; s2 += q1.x; s3 += q1.y;
    }
    #pragma unroll
    for (int o = 32; o; o >>= 1) {
        s0 += __shfl_xor(s0, o, 64);
        s1 += __shfl_xor(s1, o, 64);
        s2 += __shfl_xor(s2, o, 64);
        s3 += __shfl_xor(s3, o, 64);
    }
    float sh = head == 0 ? s0 : head == 1 ? s1 : head == 2 ? s2 : s3;
    float inv = sh > 0.f ? 1.f / sh : 0.f;

    float acc[8];
    #pragma unroll
    for (int jj = 0; jj < 8; ++jj) acc[jj] = 0.f;
    int endm1 = end - 1;
    for (int base = start; base < end; base += 32) {
        #pragma unroll
        for (int t = 0; t < 8; ++t) {               // 32 edges in flight per wave-iter
            int i = base + 4 * t + g;
            int ic = min(i, endm1);                 // clamped: always valid
            int s = src_sorted[ic];
            float a = __half2float(alpha1h[ic * 4 + head]);
            a = (i < end) ? a : 0.f;                // select, not branch
            float4 r = *(const float4*)(z1h + ((size_t)s << 7) + l16 * 8);
            const __half* zh = (const __half*)&r;
            #pragma unroll
            for (int k = 0; k < 8; ++k)             // v_fma_mix_f32
                acc[k] = fmaf(__half2float(zh[k]), a, acc[k]);
        }
    }
    #pragma unroll
    for (int jj = 0; jj < 8; ++jj) {
        acc[jj] += __shfl_xor(acc[jj], 16, 64);
        acc[jj] += __shfl_xor(acc[jj], 32, 64);
    }
    if (g == 0) {
        float xv[8];
        #pragma unroll
        for (int jj = 0; jj < 8; ++jj) {
            float t = acc[jj] * inv + b1[l16 * 8 + jj];
            xv[jj] = t > 0.f ? t : (__expf(t) - 1.f);   // elu
        }
        union { __half2 h2[4]; uint4 u; } pk;
        #pragma unroll
        for (int k = 0; k < 4; ++k) pk.h2[k] = __floats2half2_rn(xv[2 * k], xv[2 * k + 1]);
        *(uint4*)(x + ((size_t)node << 7) + l16 * 8) = pk.u;
    }
}

// ===== z2 = x @ W2 (fp16 in/out) + el2/er2 — 64 rows/block, 4 rows x 2 cols/thread =====
__global__ __launch_bounds__(256) void gemm2el_kernel(
        const __half* __restrict__ x, const float* __restrict__ W2,
        const float* __restrict__ al2, const float* __restrict__ ar2,
        __half* __restrict__ z2h, float* __restrict__ el2, float* __restrict__ er2, int N) {
    __shared__ __half xsh[64][136];   // pad 8 halves
    __shared__ float W2T[32][132];    // [c][k]
    int tid = threadIdx.x;
    int row0 = blockIdx.x * 64;
    int nrow = min(64, N - row0);

    for (int idx = tid; idx < nrow * 16; idx += 256) {
        int r = idx >> 4, kq = idx & 15;
        float4 v = ((const float4*)(x + (size_t)(row0 + r) * 128))[kq];
        *(float4*)&xsh[r][kq * 8] = v;
    }
    for (int idx = tid; idx < 4096; idx += 256) {
        int k = idx >> 5, c = idx & 31;
        W2T[c][k] = W2[idx];
    }
    __syncthreads();

    int gc = tid & 15, gr = tid >> 4;   // rows gr*4+j, cols {gc, gc+16}
    float acc[4][2];
    #pragma unroll
    for (int j = 0; j < 4; ++j) { acc[j][0] = 0.f; acc[j][1] = 0.f; }

    for (int p = 0; p < 32; ++p) {      // k-chunks of 4
        float4 w0 = *(const float4*)&W2T[gc][p * 4];
        float4 w1 = *(const float4*)&W2T[gc + 16][p * 4];
        #pragma unroll
        for (int j = 0; j < 4; ++j) {
            const __half* xr = &xsh[gr * 4 + j][p * 4];
            float x0 = __half2float(xr[0]), x1 = __half2float(xr[1]);
            float x2 = __half2float(xr[2]), x3 = __half2float(xr[3]);
            acc[j][0] = fmaf(x0, w0.x, fmaf(x1, w0.y, fmaf(x2, w0.z, fmaf(x3, w0.w, acc[j][0]))));
            acc[j][1] = fmaf(x0, w1.x, fmaf(x1, w1.y, fmaf(x2, w1.z, fmaf(x3, w1.w, acc[j][1]))));
        }
    }

    float al0 = al2[gc], al1v = al2[gc + 16];
    float ar0 = ar2[gc], ar1v = ar2[gc + 16];
    #pragma unroll
    for (int j = 0; j < 4; ++j) {
        int r = gr * 4 + j;
        int node = row0 + r;
        bool live = r < nrow;
        if (live) {
            z2h[(size_t)node * 32 + gc]      = __float2half(acc[j][0]);
            z2h[(size_t)node * 32 + gc + 16] = __float2half(acc[j][1]);
        }
        float pl = acc[j][0] * al0 + acc[j][1] * al1v;
        float pr = acc[j][0] * ar0 + acc[j][1] * ar1v;
        #pragma unroll
        for (int o = 8; o; o >>= 1) {
            pl += __shfl_xor(pl, o, 16);
            pr += __shfl_xor(pr, o, 16);
        }
        if (live && gc == 0) { el2[node] = pl; er2[node] = pr; }
    }
}

// ====== layer2: single-pass exp + SpMM (fma_mix) + bias -> out (wave/node) ======
__global__ __launch_bounds__(256) void agg2_fused(
        const int* __restrict__ src_sorted, const unsigned* __restrict__ off,
        const float* __restrict__ el2, const float* __restrict__ er2,
        const __half* __restrict__ z2h, const float* __restrict__ b2,
        float* __restrict__ out) {
    int tid = threadIdx.x, lane = tid & 63;
    int node = blockIdx.x * 4 + (tid >> 6);
    int start = (int)off[node], end = (int)off[node + 1];
    float er_d = er2[node];

    int g = lane >> 2, l4 = lane & 3;
    float acc[8];
    #pragma unroll
    for (int jj = 0; jj < 8; ++jj) acc[jj] = 0.f;
    float sloc = 0.f;
    int endm1 = end - 1;
    for (int base = start; base < end; base += 64) {
        #pragma unroll
        for (int t = 0; t < 4; ++t) {               // 64 edges in flight per wave-iter
            int i = base + 16 * t + g;
            int ic = min(i, endm1);
            int s = src_sorted[ic];
            float v = el2[s] + er_d;
            v = v > 0.f ? v : NEG_SLOPE * v;
            float ex = __expf(v);
            ex = (i < end) ? ex : 0.f;
            sloc += (l4 == 0) ? ex : 0.f;
            float4 r = *(const float4*)(z2h + ((size_t)s << 5) + l4 * 8);
            const __half* zh = (const __half*)&r;
            #pragma unroll
            for (int k = 0; k < 8; ++k)
                acc[k] = fmaf(__half2float(zh[k]), ex, acc[k]);
        }
    }
    #pragma unroll
    for (int jj = 0; jj < 8; ++jj) {
        acc[jj] += __shfl_xor(acc[jj], 4, 64);
        acc[jj] += __shfl_xor(acc[jj], 8, 64);
        acc[jj] += __shfl_xor(acc[jj], 16, 64);
        acc[jj] += __shfl_xor(acc[jj], 32, 64);
    }
    #pragma unroll
    for (int o = 32; o; o >>= 1) sloc += __shfl_xor(sloc, o, 64);
    float inv = sloc > 0.f ? 1.f / sloc : 0.f;
    if (g == 0) {
        #pragma unroll
        for (int jj = 0; jj < 8; ++jj)
            out[(size_t)node * 32 + l4 * 8 + jj] = acc[jj] * inv + b2[l4 * 8 + jj];
    }
}

extern "C" void kernel_launch(void* const* d_in, const int* in_sizes, int n_in,
                              void* d_out, int out_size, void* d_ws, size_t ws_size,
                              hipStream_t stream) {
    const float* h   = (const float*)d_in[0];
    const int*   src = (const int*)d_in[1];
    const int*   dst = (const int*)d_in[2];
    const float* W1  = (const float*)d_in[3];
    const float* al1 = (const float*)d_in[4];
    const float* ar1 = (const float*)d_in[5];
    const float* b1  = (const float*)d_in[6];
    const float* W2  = (const float*)d_in[7];
    const float* al2 = (const float*)d_in[8];
    const float* ar2 = (const float*)d_in[9];
    const float* b2  = (const float*)d_in[10];
    float* out = (float*)d_out;
    const int N = NN;
    const int E = in_sizes[1];

    char* w = (char*)d_ws;
    __half* z1h       = (__half*)w;   w += (size_t)N * 128 * 2;
    __half* z2h       = (__half*)w;   w += (size_t)N * 32 * 2;
    __half* xh        = (__half*)w;   w += (size_t)N * 128 * 2;
    int2*  ebuf       = (int2*)w;     w += (size_t)NBUCK * BCAP * 8;
    uint2* alpha1p    = (uint2*)w;    w += (size_t)E * 8;
    int*   src_sorted = (int*)w;      w += (size_t)E * 4;
    float* el1        = (float*)w;    w += (size_t)N * 4 * 4;
    float* er1        = (float*)w;    w += (size_t)N * 4 * 4;
    float* el2        = (float*)w;    w += (size_t)N * 4;
    float* er2        = (float*)w;    w += (size_t)N * 4;
    unsigned* off     = (unsigned*)w; w += (size_t)(N + 16) * 4;
    unsigned* bucket_cursor = (unsigned*)w; w += 128 * 4;

    hipMemsetAsync(bucket_cursor, 0, 128 * sizeof(unsigned), stream);
    bucketA<<<(E + 1023) / 1024, 1024, 0, stream>>>(src, dst, bucket_cursor, ebuf, E);
    gemm1_kernel<<<(N + 63) / 64, 256, 0, stream>>>(h, W1, al1, ar1, z1h, el1, er1, N);
    scatterC<<<NBUCK, 1024, 0, stream>>>(ebuf, bucket_cursor, el1, er1,
                                         off, src_sorted, alpha1p, N, E);
    agg1_spmm<<<N / 4, 256, 0, stream>>>(src_sorted, off, alpha1p, z1h, b1, xh);
    gemm2el_kernel<<<(N + 63) / 64, 256, 0, stream>>>(xh, W2, al2, ar2, z2h, el2, er2, N);
    agg2_fused<<<N / 4, 256, 0, stream>>>(src_sorted, off, el2, er2, z2h, b2, out);
}

// Round 14
// 317.321 us; speedup vs baseline: 1.1209x; 1.0088x over previous
//
#include <hip/hip_runtime.h>
#include <hip/hip_fp16.h>

#define NN 50000
#define NEG_SLOPE 0.2f
#define BSHIFT 9
#define BNODES (1 << BSHIFT)                          // 512 nodes per bucket
#define NBUCK ((NN + BNODES - 1) >> BSHIFT)           // 98
#define BCAP 18432                                    // E/NBUCK=16384 avg, +16 sigma

// ---- pass A: coarse bucket binning of (src,dst) by dst>>9 ----
// bucket_cursor[b] is RELATIVE to region start (memset-0 init)
__global__ __launch_bounds__(1024) void bucketA(
        const int* __restrict__ src, const int* __restrict__ dst,
        unsigned* __restrict__ bucket_cursor, int2* __restrict__ ebuf, int E) {
    __shared__ unsigned hist[NBUCK];
    int tid = threadIdx.x;
    if (tid < NBUCK) hist[tid] = 0u;
    __syncthreads();
    int e = blockIdx.x * 1024 + tid;
    int s = 0, d = 0, b = 0;
    bool valid = e < E;
    if (valid) {
        s = src[e]; d = dst[e]; b = d >> BSHIFT;
        atomicAdd(&hist[b], 1u);
    }
    __syncthreads();
    if (tid < NBUCK) {
        unsigned c = hist[tid];
        hist[tid] = c ? (unsigned)(tid * BCAP) + atomicAdd(&bucket_cursor[tid], c) : 0u;
    }
    __syncthreads();
    if (valid) {
        unsigned slot = atomicAdd(&hist[b], 1u);
        ebuf[slot] = make_int2(s, d);
    }
}

// ===== z1 = h @ W1 (fp16 out) + el1/er1 — 64x128 block, 8 rows x 4 cols/thread.
//       W1 streamed from global (L2-resident) -> LDS pipe only carries h. =====
__global__ __launch_bounds__(256) void gemm1_kernel(
        const float* __restrict__ h, const float* __restrict__ W1,
        const float* __restrict__ al1, const float* __restrict__ ar1,
        __half* __restrict__ z1h, float* __restrict__ el1, float* __restrict__ er1, int N) {
    __shared__ float hs[64][132];     // +4 pad: bank spread
    int tid = threadIdx.x;
    int gc = tid & 31, gr = tid >> 5;            // rows gr*8..+7, cols gc+32i (head i)
    int row0 = blockIdx.x * 64;
    int nrow = min(64, N - row0);

    for (int idx = tid; idx < nrow * 32; idx += 256) {
        int row = idx >> 5, kq = idx & 31;
        *(float4*)&hs[row][kq * 4] = ((const float4*)(h + (size_t)(row0 + row) * 128))[kq];
    }
    __syncthreads();

    float acc[8][4];
    #pragma unroll
    for (int j = 0; j < 8; ++j)
        #pragma unroll
        for (int i = 0; i < 4; ++i) acc[j][i] = 0.f;

    for (int k = 0; k < 128; k += 4) {
        float w[4][4];
        #pragma unroll
        for (int kk = 0; kk < 4; ++kk)
            #pragma unroll
            for (int i = 0; i < 4; ++i)
                w[kk][i] = W1[(k + kk) * 128 + gc + 32 * i];
        #pragma unroll
        for (int j = 0; j < 8; ++j) {
            float4 hv = *(const float4*)&hs[gr * 8 + j][k];
            #pragma unroll
            for (int i = 0; i < 4; ++i)
                acc[j][i] = fmaf(hv.x, w[0][i], fmaf(hv.y, w[1][i],
                            fmaf(hv.z, w[2][i], fmaf(hv.w, w[3][i], acc[j][i]))));
        }
    }

    float a_l[4], a_r[4];
    #pragma unroll
    for (int i = 0; i < 4; ++i) { a_l[i] = al1[gc + 32 * i]; a_r[i] = ar1[gc + 32 * i]; }

    #pragma unroll
    for (int j = 0; j < 8; ++j) {
        int row = gr * 8 + j;
        bool live = row < nrow;
        int node = row0 + row;
        if (live) {
            #pragma unroll
            for (int i = 0; i < 4; ++i)
                z1h[(size_t)node * 128 + gc + 32 * i] = __float2half(acc[j][i]);
        }
        float pl[4], pr[4];
        #pragma unroll
        for (int i = 0; i < 4; ++i) { pl[i] = acc[j][i] * a_l[i]; pr[i] = acc[j][i] * a_r[i]; }
        #pragma unroll
        for (int o = 16; o; o >>= 1) {
            #pragma unroll
            for (int i = 0; i < 4; ++i) {
                pl[i] += __shfl_xor(pl[i], o, 32);
                pr[i] += __shfl_xor(pr[i], o, 32);
            }
        }
        if (live && gc == 0) {
            #pragma unroll
            for (int i = 0; i < 4; ++i) {
                el1[node * 4 + i] = pl[i];
                er1[node * 4 + i] = pr[i];
            }
        }
    }
}

// ---- scatterC: per-bucket LDS hist/scan/rank; writes off[], src_sorted[],
//      and per-edge fp16 alpha (exp of leaky score). NO per-node sums here
//      (LDS same-address atomics serialize — R12 lesson). ----
__global__ __launch_bounds__(1024) void scatterC(
        const int2* __restrict__ ebuf, const unsigned* __restrict__ bucket_cursor,
        const float* __restrict__ el1, const float* __restrict__ er1,
        unsigned* __restrict__ off, int* __restrict__ src_sorted,
        uint2* __restrict__ alpha1p, int N, int E) {
    __shared__ unsigned hist[BNODES], nodeoff[BNODES], wsum[8], bsz[128];
    __shared__ float4 er_s[BNODES];
    int b = blockIdx.x, tid = threadIdx.x;
    int base = b << BSHIFT;
    unsigned rs = (unsigned)(b * BCAP), re = rs + bucket_cursor[b];
    const float4* el1v = (const float4*)el1;
    const float4* er1v = (const float4*)er1;

    if (tid < 128) bsz[tid] = (tid < NBUCK) ? bucket_cursor[tid] : 0u;
    if (tid < BNODES) {
        hist[tid] = 0u;
        int n = base + tid;
        er_s[tid] = (n < N) ? er1v[n] : make_float4(0.f, 0.f, 0.f, 0.f);
    }
    __syncthreads();
    if (tid == 0) {
        unsigned r = 0;
        for (int t = 0; t < NBUCK; ++t) { unsigned c = bsz[t]; bsz[t] = r; r += c; }
        if (b == 0) off[N] = (unsigned)E;
    }
    __syncthreads();
    unsigned boff = bsz[b];

    for (unsigned i = rs + tid; i < re; i += 1024)
        atomicAdd(&hist[ebuf[i].y - base], 1u);
    __syncthreads();
    unsigned v = 0, x = 0;
    int lane = tid & 63, wv = tid >> 6;
    if (tid < BNODES) {
        v = hist[tid]; x = v;
        #pragma unroll
        for (int o = 1; o < 64; o <<= 1) {
            unsigned n = __shfl_up(x, o, 64);
            if (lane >= o) x += n;
        }
        if (lane == 63) wsum[wv] = x;
    }
    __syncthreads();
    if (tid == 0) {
        unsigned r = 0;
        #pragma unroll
        for (int k = 0; k < 8; ++k) { unsigned t = wsum[k]; wsum[k] = r; r += t; }
    }
    __syncthreads();
    if (tid < BNODES) {
        unsigned exoff = x - v + wsum[wv] + boff;
        nodeoff[tid] = exoff;
        if (base + tid < N) off[base + tid] = exoff;
        hist[tid] = 0u;
    }
    __syncthreads();
    // rank + write src_sorted and fp16 alpha (softmax shift dropped: bounded scores)
    for (unsigned i = rs + tid; i < re; i += 1024) {
        int2 ed = ebuf[i];
        int ln = ed.y - base;
        unsigned r = atomicAdd(&hist[ln], 1u);
        unsigned p = nodeoff[ln] + r;
        src_sorted[p] = ed.x;
        float4 el = el1v[ed.x];
        float4 er = er_s[ln];
        float v0 = el.x + er.x; v0 = v0 > 0.f ? v0 : NEG_SLOPE * v0;
        float v1 = el.y + er.y; v1 = v1 > 0.f ? v1 : NEG_SLOPE * v1;
        float v2 = el.z + er.z; v2 = v2 > 0.f ? v2 : NEG_SLOPE * v2;
        float v3 = el.w + er.w; v3 = v3 > 0.f ? v3 : NEG_SLOPE * v3;
        union { __half2 h2[2]; uint2 u; } pk;
        pk.h2[0] = __floats2half2_rn(__expf(v0), __expf(v1));
        pk.h2[1] = __floats2half2_rn(__expf(v2), __expf(v3));
        alpha1p[p] = pk.u;
    }
}

// ====== layer1: gather-SpMM, 8-lane group/edge (16 cols/lane), in-loop alpha sum ======
__global__ __launch_bounds__(256) void agg1_spmm(
        const int* __restrict__ src_sorted, const unsigned* __restrict__ off,
        const uint2* __restrict__ alpha1p, const __half* __restrict__ z1h,
        const float* __restrict__ b1, __half* __restrict__ x) {
    int tid = threadIdx.x, lane = tid & 63, w = tid >> 6;
    int node = blockIdx.x * 4 + w;
    int start = (int)off[node], end = (int)off[node + 1];
    int g = lane >> 3, l8 = lane & 7, head = l8 >> 1;
    const __half* alpha1h = (const __half*)alpha1p;

    float acc[16];
    #pragma unroll
    for (int jj = 0; jj < 16; ++jj) acc[jj] = 0.f;
    float sloc = 0.f;
    int endm1 = end - 1;
    for (int base = start; base < end; base += 32) {
        #pragma unroll
        for (int t = 0; t < 4; ++t) {               // 32 edges in flight per wave-iter
            int i = base + 8 * t + g;
            int ic = min(i, endm1);                 // clamped: always valid
            int s = src_sorted[ic];
            float a = __half2float(alpha1h[ic * 4 + head]);
            a = (i < end) ? a : 0.f;                // select, not branch
            sloc += ((l8 & 1) == 0) ? a : 0.f;      // count each edge-head once
            const __half* zr = z1h + ((size_t)s << 7) + l8 * 16;
            float4 r0 = *(const float4*)zr;
            float4 r1 = *(const float4*)(zr + 8);
            const __half* zh0 = (const __half*)&r0;
            const __half* zh1 = (const __half*)&r1;
            #pragma unroll
            for (int k = 0; k < 8; ++k) {           // v_fma_mix_f32
                acc[k]     = fmaf(__half2float(zh0[k]), a, acc[k]);
                acc[k + 8] = fmaf(__half2float(zh1[k]), a, acc[k + 8]);
            }
        }
    }
    #pragma unroll
    for (int jj = 0; jj < 16; ++jj) {
        acc[jj] += __shfl_xor(acc[jj], 8, 64);
        acc[jj] += __shfl_xor(acc[jj], 16, 64);
        acc[jj] += __shfl_xor(acc[jj], 32, 64);
    }
    // spread pair (xor1), then sum across the 8 groups
    sloc += __shfl_xor(sloc, 1, 64);
    sloc += __shfl_xor(sloc, 8, 64);
    sloc += __shfl_xor(sloc, 16, 64);
    sloc += __shfl_xor(sloc, 32, 64);
    float inv = sloc > 0.f ? 1.f / sloc : 0.f;

    if (g == 0) {
        float xv[16];
        #pragma unroll
        for (int jj = 0; jj < 16; ++jj) {
            float t = acc[jj] * inv + b1[l8 * 16 + jj];
            xv[jj] = t > 0.f ? t : (__expf(t) - 1.f);   // elu
        }
        union { __half2 h2[8]; uint4 u[2]; } pk;
        #pragma unroll
        for (int k = 0; k < 8; ++k) pk.h2[k] = __floats2half2_rn(xv[2 * k], xv[2 * k + 1]);
        uint4* xp = (uint4*)(x + ((size_t)node << 7) + l8 * 16);
        xp[0] = pk.u[0];
        xp[1] = pk.u[1];
    }
}

// ===== z2 = x @ W2 (fp16 in/out) + el2/er2 — 64 rows/block, 4 rows x 2 cols/thread =====
__global__ __launch_bounds__(256) void gemm2el_kernel(
        const __half* __restrict__ x, const float* __restrict__ W2,
        const float* __restrict__ al2, const float* __restrict__ ar2,
        __half* __restrict__ z2h, float* __restrict__ el2, float* __restrict__ er2, int N) {
    __shared__ __half xsh[64][136];   // pad 8 halves
    __shared__ float W2T[32][132];    // [c][k]
    int tid = threadIdx.x;
    int row0 = blockIdx.x * 64;
    int nrow = min(64, N - row0);

    for (int idx = tid; idx < nrow * 16; idx += 256) {
        int r = idx >> 4, kq = idx & 15;
        float4 v = ((const float4*)(x + (size_t)(row0 + r) * 128))[kq];
        *(float4*)&xsh[r][kq * 8] = v;
    }
    for (int idx = tid; idx < 4096; idx += 256) {
        int k = idx >> 5, c = idx & 31;
        W2T[c][k] = W2[idx];
    }
    __syncthreads();

    int gc = tid & 15, gr = tid >> 4;   // rows gr*4+j, cols {gc, gc+16}
    float acc[4][2];
    #pragma unroll
    for (int j = 0; j < 4; ++j) { acc[j][0] = 0.f; acc[j][1] = 0.f; }

    for (int p = 0; p < 32; ++p) {      // k-chunks of 4
        float4 w0 = *(const float4*)&W2T[gc][p * 4];
        float4 w1 = *(const float4*)&W2T[gc + 16][p * 4];
        #pragma unroll
        for (int j = 0; j < 4; ++j) {
            const __half* xr = &xsh[gr * 4 + j][p * 4];
            float x0 = __half2float(xr[0]), x1 = __half2float(xr[1]);
            float x2 = __half2float(xr[2]), x3 = __half2float(xr[3]);
            acc[j][0] = fmaf(x0, w0.x, fmaf(x1, w0.y, fmaf(x2, w0.z, fmaf(x3, w0.w, acc[j][0]))));
            acc[j][1] = fmaf(x0, w1.x, fmaf(x1, w1.y, fmaf(x2, w1.z, fmaf(x3, w1.w, acc[j][1]))));
        }
    }

    float al0 = al2[gc], al1v = al2[gc + 16];
    float ar0 = ar2[gc], ar1v = ar2[gc + 16];
    #pragma unroll
    for (int j = 0; j < 4; ++j) {
        int r = gr * 4 + j;
        int node = row0 + r;
        bool live = r < nrow;
        if (live) {
            z2h[(size_t)node * 32 + gc]      = __float2half(acc[j][0]);
            z2h[(size_t)node * 32 + gc + 16] = __float2half(acc[j][1]);
        }
        float pl = acc[j][0] * al0 + acc[j][1] * al1v;
        float pr = acc[j][0] * ar0 + acc[j][1] * ar1v;
        #pragma unroll
        for (int o = 8; o; o >>= 1) {
            pl += __shfl_xor(pl, o, 16);
            pr += __shfl_xor(pr, o, 16);
        }
        if (live && gc == 0) { el2[node] = pl; er2[node] = pr; }
    }
}

// ====== layer2: single-pass exp + SpMM (fma_mix) + bias -> out (wave/node) ======
__global__ __launch_bounds__(256) void agg2_fused(
        const int* __restrict__ src_sorted, const unsigned* __restrict__ off,
        const float* __restrict__ el2, const float* __restrict__ er2,
        const __half* __restrict__ z2h, const float* __restrict__ b2,
        float* __restrict__ out) {
    int tid = threadIdx.x, lane = tid & 63;
    int node = blockIdx.x * 4 + (tid >> 6);
    int start = (int)off[node], end = (int)off[node + 1];
    float er_d = er2[node];

    int g = lane >> 2, l4 = lane & 3;
    float acc[8];
    #pragma unroll
    for (int jj = 0; jj < 8; ++jj) acc[jj] = 0.f;
    float sloc = 0.f;
    int endm1 = end - 1;
    for (int base = start; base < end; base += 64) {
        #pragma unroll
        for (int t = 0; t < 4; ++t) {               // 64 edges in flight per wave-iter
            int i = base + 16 * t + g;
            int ic = min(i, endm1);
            int s = src_sorted[ic];
            float v = el2[s] + er_d;
            v = v > 0.f ? v : NEG_SLOPE * v;
            float ex = __expf(v);
            ex = (i < end) ? ex : 0.f;
            sloc += (l4 == 0) ? ex : 0.f;
            float4 r = *(const float4*)(z2h + ((size_t)s << 5) + l4 * 8);
            const __half* zh = (const __half*)&r;
            #pragma unroll
            for (int k = 0; k < 8; ++k)
                acc[k] = fmaf(__half2float(zh[k]), ex, acc[k]);
        }
    }
    #pragma unroll
    for (int jj = 0; jj < 8; ++jj) {
        acc[jj] += __shfl_xor(acc[jj], 4, 64);
        acc[jj] += __shfl_xor(acc[jj], 8, 64);
        acc[jj] += __shfl_xor(acc[jj], 16, 64);
        acc[jj] += __shfl_xor(acc[jj], 32, 64);
    }
    #pragma unroll
    for (int o = 32; o; o >>= 1) sloc += __shfl_xor(sloc, o, 64);
    float inv = sloc > 0.f ? 1.f / sloc : 0.f;
    if (g == 0) {
        #pragma unroll
        for (int jj = 0; jj < 8; ++jj)
            out[(size_t)node * 32 + l4 * 8 + jj] = acc[jj] * inv + b2[l4 * 8 + jj];
    }
}

extern "C" void kernel_launch(void* const* d_in, const int* in_sizes, int n_in,
                              void* d_out, int out_size, void* d_ws, size_t ws_size,
                              hipStream_t stream) {
    const float* h   = (const float*)d_in[0];
    const int*   src = (const int*)d_in[1];
    const int*   dst = (const int*)d_in[2];
    const float* W1  = (const float*)d_in[3];
    const float* al1 = (const float*)d_in[4];
    const float* ar1 = (const float*)d_in[5];
    const float* b1  = (const float*)d_in[6];
    const float* W2  = (const float*)d_in[7];
    const float* al2 = (const float*)d_in[8];
    const float* ar2 = (const float*)d_in[9];
    const float* b2  = (const float*)d_in[10];
    float* out = (float*)d_out;
    const int N = NN;
    const int E = in_sizes[1];

    char* w = (char*)d_ws;
    __half* z1h       = (__half*)w;   w += (size_t)N * 128 * 2;
    __half* z2h       = (__half*)w;   w += (size_t)N * 32 * 2;
    __half* xh        = (__half*)w;   w += (size_t)N * 128 * 2;
    int2*  ebuf       = (int2*)w;     w += (size_t)NBUCK * BCAP * 8;
    uint2* alpha1p    = (uint2*)w;    w += (size_t)E * 8;
    int*   src_sorted = (int*)w;      w += (size_t)E * 4;
    float* el1        = (float*)w;    w += (size_t)N * 4 * 4;
    float* er1        = (float*)w;    w += (size_t)N * 4 * 4;
    float* el2        = (float*)w;    w += (size_t)N * 4;
    float* er2        = (float*)w;    w += (size_t)N * 4;
    unsigned* off     = (unsigned*)w; w += (size_t)(N + 16) * 4;
    unsigned* bucket_cursor = (unsigned*)w; w += 128 * 4;

    hipMemsetAsync(bucket_cursor, 0, 128 * sizeof(unsigned), stream);
    bucketA<<<(E + 1023) / 1024, 1024, 0, stream>>>(src, dst, bucket_cursor, ebuf, E);
    gemm1_kernel<<<(N + 63) / 64, 256, 0, stream>>>(h, W1, al1, ar1, z1h, el1, er1, N);
    scatterC<<<NBUCK, 1024, 0, stream>>>(ebuf, bucket_cursor, el1, er1,
                                         off, src_sorted, alpha1p, N, E);
    agg1_spmm<<<N / 4, 256, 0, stream>>>(src_sorted, off, alpha1p, z1h, b1, xh);
    gemm2el_kernel<<<(N + 63) / 64, 256, 0, stream>>>(xh, W2, al2, ar2, z2h, el2, er2, N);
    agg2_fused<<<N / 4, 256, 0, stream>>>(src_sorted, off, el2, er2, z2h, b2, out);
}